// Round 5
// baseline (337.895 us; speedup 1.0000x reference)
//
#include <hip/hip_runtime.h>

// Problem constants
static constexpr int Bn  = 64;     // batch
static constexpr int T   = 2048;   // angles
static constexpr int NA  = 256;    // atoms
static constexpr int DA  = 256;    // d_atom (K1)
static constexpr int DH  = 512;    // d_hid  (N1 / K2)
static constexpr int DO  = 256;    // d_out  (N2)
static constexpr int M   = Bn * T;         // 131072 rows
static constexpr int NBS = M / 128;        // 1024 stat blocks
static constexpr int NBC = M / 64;         // 2048 output blocks

typedef __attribute__((ext_vector_type(4))) float  f32x4;
typedef __attribute__((ext_vector_type(8))) __bf16 bf16x8;
typedef __attribute__((ext_vector_type(8))) short  short8;

__device__ __forceinline__ unsigned short f2bf(float f) {
  union { float f; unsigned u; } v; v.f = f;
  unsigned u = v.u + 0x7FFFu + ((v.u >> 16) & 1u);   // RNE
  return (unsigned short)(u >> 16);
}
__device__ __forceinline__ float bf2f(unsigned short b) {
  union { unsigned u; float f; } v; v.u = ((unsigned)b) << 16;
  return v.f;
}

// ---------------------------------------------------------------------------
// prep: W1 [256x512] f32 -> W1T [512][256] bf16 ; W2 [512x256] f32 -> W2T [256][512] bf16
// ---------------------------------------------------------------------------
__global__ void prep_kernel(const float* __restrict__ W1, const float* __restrict__ W2,
                            unsigned short* __restrict__ W1T, unsigned short* __restrict__ W2T) {
  int id = blockIdx.x * 256 + threadIdx.x;           // 131072 threads
  {
    int n = id >> 8, k = id & 255;                   // W1T[n][k] = W1[k][n]
    W1T[id] = f2bf(W1[k * DH + n]);
  }
  {
    int n = id >> 9, k = id & 511;                   // W2T[n][k] = W2[k][n]
    W2T[id] = f2bf(W2[k * DO + n]);
  }
}

// ---------------------------------------------------------------------------
// kA: zW = bf16(z @ W1).  16384 x 512, K=256.  (unchanged from round 4)
// ---------------------------------------------------------------------------
__global__ __launch_bounds__(512, 4) void kA_zw(
    const float* __restrict__ z, const unsigned short* __restrict__ W1T,
    unsigned short* __restrict__ zW) {
  __shared__ __align__(16) unsigned short As[32][64][8];      // [g][row][8] 32KB
  const int tid = threadIdx.x;
  const int xcd = blockIdx.x & 7, idx = blockIdx.x >> 3;
  const int bm = xcd * 32 + (idx >> 1), bn = idx & 1;         // batches 8x..8x+7 on XCD x
  const int row0 = bm * 64, n0b = bn * 256;
  const int wave = tid >> 6, lane = tid & 63, ql = lane >> 4, r16 = lane & 15;
  const int gq = tid >> 8, t8 = tid & 255;
  const int gr = t8 >> 2, sub = t8 & 3;
  const int sxw = (sub << 2) ^ sub;                  // store row swizzle (g&3 = sub)
  const int sxr = (ql << 2) ^ ql;                    // read swizzle (g&3 = ql)

  // per-lane B pointer: frag(nf, s) = 16B at bp + nf*16*DA + s*32
  const unsigned short* bp = W1T + (size_t)(n0b + wave * 32 + r16) * DA + ql * 8;

  bf16x8 bq[2][2];
#pragma unroll
  for (int p = 0; p < 2; ++p)
#pragma unroll
    for (int nf = 0; nf < 2; ++nf)
      bq[p][nf] = *(const bf16x8*)(bp + nf * 16 * DA + p * 32);

  // ---- produce full A tile: z rows f32 -> bf16, swizzled rows ----
  {
    const float* zr = z + (size_t)(row0 + gr) * DA + sub * 8;
#pragma unroll
    for (int cl = 0; cl < 4; ++cl) {
      const int cg = gq * 4 + cl;
      f32x4 a0 = *(const f32x4*)(zr + cg * 32);
      f32x4 a1 = *(const f32x4*)(zr + cg * 32 + 4);
      bf16x8 pk;
#pragma unroll
      for (int j = 0; j < 4; ++j) { pk[j] = (__bf16)a0[j]; pk[4 + j] = (__bf16)a1[j]; }
      *(bf16x8*)&As[cg * 4 + sub][gr ^ sxw][0] = pk;
    }
  }
  __syncthreads();

  f32x4 acc[4][2] = {};
#pragma unroll
  for (int s = 0; s < 8; ++s) {
    bf16x8 afr[4], bfr[2];
#pragma unroll
    for (int mf = 0; mf < 4; ++mf)
      afr[mf] = *(const bf16x8*)&As[s * 4 + ql][(mf * 16 + r16) ^ sxr][0];
#pragma unroll
    for (int nf = 0; nf < 2; ++nf) bfr[nf] = bq[s & 1][nf];
    __builtin_amdgcn_s_setprio(1);
#pragma unroll
    for (int mf = 0; mf < 4; ++mf)
#pragma unroll
      for (int nf = 0; nf < 2; ++nf)
        acc[mf][nf] = __builtin_amdgcn_mfma_f32_16x16x32_bf16(afr[mf], bfr[nf], acc[mf][nf], 0, 0, 0);
    __builtin_amdgcn_s_setprio(0);
    if (s + 2 < 8) {
#pragma unroll
      for (int nf = 0; nf < 2; ++nf)
        bq[s & 1][nf] = *(const bf16x8*)(bp + nf * 16 * DA + (s + 2) * 32);
    }
  }

  const int n0 = n0b + wave * 32;
#pragma unroll
  for (int nf = 0; nf < 2; ++nf) {
    const int col = n0 + nf * 16 + r16;
#pragma unroll
    for (int mf = 0; mf < 4; ++mf)
#pragma unroll
      for (int p = 0; p < 4; ++p)
        zW[(size_t)(row0 + mf * 16 + ql * 4 + p) * DH + col] = f2bf(acc[mf][nf][p]);
  }
}

// ---------------------------------------------------------------------------
// kB: column stats of s = zW[a0]+zW[a1]+zW[a2].  (unchanged from round 4)
// ---------------------------------------------------------------------------
__global__ __launch_bounds__(256) void kB_stats(
    const unsigned short* __restrict__ zW, const int* __restrict__ tbl,
    float* __restrict__ psum, float* __restrict__ psq) {
  __shared__ int idxs[128][3];
  __shared__ float red1[4][512];
  __shared__ float red2[4][512];
  const int bid = blockIdx.x;
  const int blk = (bid & 7) * (NBS >> 3) + (bid >> 3);   // XCD-chunk swizzle (bijective)
  const int tid = threadIdx.x;
  const int row0 = blk * 128;
  const unsigned short* zWb = zW + (size_t)(row0 >> 11) * NA * DH;

  for (int i = tid; i < 384; i += 256) ((int*)idxs)[i] = tbl[(size_t)row0 * 3 + i];
  __syncthreads();

  const int cc = tid & 63, rg = tid >> 6;
  float s1[8] = {0, 0, 0, 0, 0, 0, 0, 0};
  float s2[8] = {0, 0, 0, 0, 0, 0, 0, 0};
#pragma unroll 8
  for (int i = 0; i < 32; ++i) {
    const int r = rg * 32 + i;
    const unsigned short* p0 = zWb + (size_t)idxs[r][0] * DH + cc * 8;
    const unsigned short* p1 = zWb + (size_t)idxs[r][1] * DH + cc * 8;
    const unsigned short* p2 = zWb + (size_t)idxs[r][2] * DH + cc * 8;
    short8 v0 = *(const short8*)p0;
    short8 v1 = *(const short8*)p1;
    short8 v2 = *(const short8*)p2;
#pragma unroll
    for (int j = 0; j < 8; ++j) {
      float h = bf2f((unsigned short)v0[j]) + bf2f((unsigned short)v1[j]) + bf2f((unsigned short)v2[j]);
      s1[j] += h;
      s2[j] = fmaf(h, h, s2[j]);
    }
  }
#pragma unroll
  for (int j = 0; j < 8; ++j) { red1[rg][cc * 8 + j] = s1[j]; red2[rg][cc * 8 + j] = s2[j]; }
  __syncthreads();
  for (int c = tid; c < 512; c += 256) {
    psum[(size_t)c * NBS + blk] = red1[0][c] + red1[1][c] + red1[2][c] + red1[3][c];
    psq [(size_t)c * NBS + blk] = red2[0][c] + red2[1][c] + red2[2][c] + red2[3][c];
  }
}

// ---------------------------------------------------------------------------
// k2: reduce partials -> a = gamma*rsqrt(var+eps), d = beta - mean*a
// ---------------------------------------------------------------------------
__global__ void k2_stats(const float* __restrict__ psum, const float* __restrict__ psq,
                         const float* __restrict__ gamma, const float* __restrict__ beta,
                         float* __restrict__ coef) {
  const int col = blockIdx.x, lane = threadIdx.x;
  float s1 = 0.f, s2 = 0.f;
  for (int i = lane; i < NBS; i += 64) {
    s1 += psum[(size_t)col * NBS + i];
    s2 += psq [(size_t)col * NBS + i];
  }
#pragma unroll
  for (int d = 1; d < 64; d <<= 1) { s1 += __shfl_xor(s1, d); s2 += __shfl_xor(s2, d); }
  if (lane == 0) {
    const float inv = 1.0f / (float)M;
    float mean = s1 * inv;
    float var  = s2 * inv - mean * mean;
    float a = gamma[col] * rsqrtf(var + 1e-5f);
    coef[col]      = a;
    coef[DH + col] = beta[col] - mean * a;
  }
}

// ---------------------------------------------------------------------------
// kC: out = relu((zW[a0]+zW[a1]+zW[a2])*a + d) @ W2 + b2
// 2048 blocks x 512 threads. Wave = (row-half rg2: 32 rows) x (col-quarter cg:
// 64 cols), acc[2][4]. A tile [g][row] in 32KB LDS, phys row = row ^ (g&7)
// (bank-uniform stores AND reads). Direct tbl reads (no idxs LDS stage).
// Cross-half prefetch: h1's g0/g1 gathers fly under h0's MFMA steps.
// B from 2-deep per-wave register queue (W2T per-lane contiguous frags).
// ---------------------------------------------------------------------------
__global__ __launch_bounds__(512, 4) void kC_out(
    const unsigned short* __restrict__ zW, const int* __restrict__ tbl,
    const unsigned short* __restrict__ W2T, const float* __restrict__ coef,
    const float* __restrict__ b2, float* __restrict__ out) {
  __shared__ __align__(16) unsigned short As[32][64][8];   // [g][row][8] 32KB
  __shared__ float aC[DH], dC[DH];

  const int bid = blockIdx.x;
  const int blk = (bid & 7) * (NBC >> 3) + (bid >> 3);     // XCD-chunk swizzle (bijective)
  const int tid = threadIdx.x;
  const int row0 = blk * 64;
  const unsigned short* zWb = zW + (size_t)(row0 >> 11) * NA * DH;

  aC[tid] = coef[tid];
  dC[tid] = coef[DH + tid];

  // ---- direct tbl read (broadcast across the 8 k-threads of a row) ----
  const int gr = tid >> 3, sc = tid & 7;                   // 64 rows x 8 k-threads
  const size_t tb = (size_t)(row0 + gr) * 3;
  const int i0 = tbl[tb], i1 = tbl[tb + 1], i2 = tbl[tb + 2];
  const unsigned short* g0p = zWb + (size_t)i0 * DH + sc * 8;
  const unsigned short* g1p = zWb + (size_t)i1 * DH + sc * 8;
  const unsigned short* g2p = zWb + (size_t)i2 * DH + sc * 8;

  // ---- issue h0 gathers immediately (fly under the coef barrier) ----
  short8 a0[4], a1[4], a2[4];
#pragma unroll
  for (int it = 0; it < 4; ++it) {
    a0[it] = *(const short8*)(g0p + it * 64);
    a1[it] = *(const short8*)(g1p + it * 64);
    a2[it] = *(const short8*)(g2p + it * 64);
  }

  const int wave = tid >> 6, lane = tid & 63, ql = lane >> 4, r16 = lane & 15;
  const int rg2 = wave >> 2;                               // row half (0/1)
  const int cg  = wave & 3;                                // col quarter

  // per-lane B pointer: frag(nf, sg) = 16B at bp + nf*16*DH + sg*32
  const unsigned short* bp = W2T + (size_t)(cg * 64 + r16) * DH + ql * 8;
  bf16x8 bq[2][4];
#pragma unroll
  for (int p = 0; p < 2; ++p)
#pragma unroll
    for (int nf = 0; nf < 4; ++nf)
      bq[p][nf] = *(const bf16x8*)(bp + nf * 16 * DH + p * 32);

  __syncthreads();                                         // coefs visible

  // ---- A-phase h0: sum + affine + relu -> bf16 As ----
#pragma unroll
  for (int it = 0; it < 4; ++it) {
    const int kk = it * 64 + sc * 8;
    f32x4 av0 = *(const f32x4*)&aC[kk];
    f32x4 av1 = *(const f32x4*)&aC[kk + 4];
    f32x4 dv0 = *(const f32x4*)&dC[kk];
    f32x4 dv1 = *(const f32x4*)&dC[kk + 4];
    bf16x8 pk;
#pragma unroll
    for (int j = 0; j < 4; ++j) {
      float h0 = bf2f((unsigned short)a0[it][j]) + bf2f((unsigned short)a1[it][j]) + bf2f((unsigned short)a2[it][j]);
      float f0 = fmaf(h0, av0[j], dv0[j]);
      f0 = f0 > 0.f ? f0 : 0.f;
      pk[j] = (__bf16)f0;
      float h1 = bf2f((unsigned short)a0[it][4 + j]) + bf2f((unsigned short)a1[it][4 + j]) + bf2f((unsigned short)a2[it][4 + j]);
      float f1 = fmaf(h1, av1[j], dv1[j]);
      f1 = f1 > 0.f ? f1 : 0.f;
      pk[4 + j] = (__bf16)f1;
    }
    *(bf16x8*)&As[it * 8 + sc][gr ^ sc][0] = pk;           // phys row = row ^ (g&7)
  }

  // ---- prefetch h1 g0/g1 (fly under h0 MFMA) ----
  short8 p0[4], p1[4];
#pragma unroll
  for (int it = 0; it < 4; ++it) {
    p0[it] = *(const short8*)(g0p + 256 + it * 64);
    p1[it] = *(const short8*)(g1p + 256 + it * 64);
  }

  asm volatile("s_waitcnt lgkmcnt(0)" ::: "memory");       // A stores visible
  __builtin_amdgcn_s_barrier();
  __builtin_amdgcn_sched_barrier(0);

  f32x4 acc[2][4] = {};

  // ---- MFMA h0 (8 barrier-free steps) ----
#pragma unroll
  for (int s = 0; s < 8; ++s) {
    const int swz = ((s & 1) << 2) | ql;                   // (s*4+ql)&7
    bf16x8 afr[2], bfr[4];
#pragma unroll
    for (int mf = 0; mf < 2; ++mf)
      afr[mf] = *(const bf16x8*)&As[s * 4 + ql][(rg2 * 32 + mf * 16 + r16) ^ swz][0];
#pragma unroll
    for (int nf = 0; nf < 4; ++nf) bfr[nf] = bq[s & 1][nf];
    __builtin_amdgcn_s_setprio(1);
#pragma unroll
    for (int mf = 0; mf < 2; ++mf)
#pragma unroll
      for (int nf = 0; nf < 4; ++nf)
        acc[mf][nf] = __builtin_amdgcn_mfma_f32_16x16x32_bf16(afr[mf], bfr[nf], acc[mf][nf], 0, 0, 0);
    __builtin_amdgcn_s_setprio(0);
    // B lookahead for step s+2 (covers into h1: targets 2..9)
#pragma unroll
    for (int nf = 0; nf < 4; ++nf)
      bq[s & 1][nf] = *(const bf16x8*)(bp + nf * 16 * DH + (s + 2) * 32);
  }

  __builtin_amdgcn_s_barrier();                            // As WAR before overwrite

  // ---- g2 h1 loads (short exposure, MLP over 4) ----
  short8 p2[4];
#pragma unroll
  for (int it = 0; it < 4; ++it)
    p2[it] = *(const short8*)(g2p + 256 + it * 64);

  // ---- A-phase h1 from prefetched registers ----
#pragma unroll
  for (int it = 0; it < 4; ++it) {
    const int kk = 256 + it * 64 + sc * 8;
    f32x4 av0 = *(const f32x4*)&aC[kk];
    f32x4 av1 = *(const f32x4*)&aC[kk + 4];
    f32x4 dv0 = *(const f32x4*)&dC[kk];
    f32x4 dv1 = *(const f32x4*)&dC[kk + 4];
    bf16x8 pk;
#pragma unroll
    for (int j = 0; j < 4; ++j) {
      float h0 = bf2f((unsigned short)p0[it][j]) + bf2f((unsigned short)p1[it][j]) + bf2f((unsigned short)p2[it][j]);
      float f0 = fmaf(h0, av0[j], dv0[j]);
      f0 = f0 > 0.f ? f0 : 0.f;
      pk[j] = (__bf16)f0;
      float h1 = bf2f((unsigned short)p0[it][4 + j]) + bf2f((unsigned short)p1[it][4 + j]) + bf2f((unsigned short)p2[it][4 + j]);
      float f1 = fmaf(h1, av1[j], dv1[j]);
      f1 = f1 > 0.f ? f1 : 0.f;
      pk[4 + j] = (__bf16)f1;
    }
    *(bf16x8*)&As[it * 8 + sc][gr ^ sc][0] = pk;
  }
  asm volatile("s_waitcnt lgkmcnt(0)" ::: "memory");
  __builtin_amdgcn_s_barrier();
  __builtin_amdgcn_sched_barrier(0);

  // ---- MFMA h1 ----
#pragma unroll
  for (int s = 0; s < 8; ++s) {
    const int sg = 8 + s;
    const int swz = ((s & 1) << 2) | ql;
    bf16x8 afr[2], bfr[4];
#pragma unroll
    for (int mf = 0; mf < 2; ++mf)
      afr[mf] = *(const bf16x8*)&As[s * 4 + ql][(rg2 * 32 + mf * 16 + r16) ^ swz][0];
#pragma unroll
    for (int nf = 0; nf < 4; ++nf) bfr[nf] = bq[sg & 1][nf];
    __builtin_amdgcn_s_setprio(1);
#pragma unroll
    for (int mf = 0; mf < 2; ++mf)
#pragma unroll
      for (int nf = 0; nf < 4; ++nf)
        acc[mf][nf] = __builtin_amdgcn_mfma_f32_16x16x32_bf16(afr[mf], bfr[nf], acc[mf][nf], 0, 0, 0);
    __builtin_amdgcn_s_setprio(0);
    if (sg + 2 < 16) {
#pragma unroll
      for (int nf = 0; nf < 4; ++nf)
        bq[sg & 1][nf] = *(const bf16x8*)(bp + nf * 16 * DH + (sg + 2) * 32);
    }
  }

  // ---- epilogue ----
  const int c0 = cg * 64, r0w = row0 + rg2 * 32;
#pragma unroll
  for (int nf = 0; nf < 4; ++nf) {
    const int col = c0 + nf * 16 + r16;
    const float bv = b2[col];
#pragma unroll
    for (int mf = 0; mf < 2; ++mf)
#pragma unroll
      for (int p = 0; p < 4; ++p)
        out[(size_t)(r0w + mf * 16 + ql * 4 + p) * DO + col] = acc[mf][nf][p] + bv;
  }
}

// ---------------------------------------------------------------------------
// workspace layout (bytes):
//   [0,256K)      W1T bf16 [512][256]
//   [256K,512K)   W2T bf16 [256][512]
//   [512K,516K)   coef f32 [1024] (a then d)
//   [2M,4M)       psum f32 [512][1024]
//   [4M,6M)       psumsq f32 [512][1024]
//   [16M,32M)     zW bf16 [16384][512]
// ---------------------------------------------------------------------------
extern "C" void kernel_launch(void* const* d_in, const int* in_sizes, int n_in,
                              void* d_out, int out_size, void* d_ws, size_t ws_size,
                              hipStream_t stream) {
  const float* z     = (const float*)d_in[0];
  const int*   tbl   = (const int*)d_in[1];
  const float* W1    = (const float*)d_in[2];
  // d_in[3] = b1: unused — BatchNorm cancels a constant column shift exactly
  const float* gamma = (const float*)d_in[4];
  const float* beta  = (const float*)d_in[5];
  const float* W2    = (const float*)d_in[6];
  const float* b2    = (const float*)d_in[7];
  float* out = (float*)d_out;

  char* ws = (char*)d_ws;
  unsigned short* W1T  = (unsigned short*)(ws);
  unsigned short* W2T  = (unsigned short*)(ws + (256 << 10));
  float*          coef = (float*)(ws + (512 << 10));
  float*          psum = (float*)(ws + (2 << 20));
  float*          psq  = (float*)(ws + (4 << 20));
  unsigned short* zW   = (unsigned short*)(ws + (16 << 20));

  prep_kernel<<<512, 256, 0, stream>>>(W1, W2, W1T, W2T);
  kA_zw<<<512, 512, 0, stream>>>(z, W1T, zW);
  kB_stats<<<NBS, 256, 0, stream>>>(zW, tbl, psum, psq);
  k2_stats<<<DH, 64, 0, stream>>>(psum, psq, gamma, beta, coef);
  kC_out<<<NBC, 512, 0, stream>>>(zW, tbl, W2T, coef, b2, out);
}